// Round 4
// baseline (160.198 us; speedup 1.0000x reference)
//
#include <hip/hip_runtime.h>
#include <math.h>

#define FEAT 512

// Output layout (float32), flat concat:
//   A_real [1024,256,256] @ 0
//   A_imag [1024,256,256] @ 67108864
//   D_real [1024,16,16]   @ 134217728
//   D_imag [1024,16,16]   @ 134479872
//   C      [256,16]       @ 134742016
#define A_IMAG_OFF 67108864
#define DR_OFF     134217728
#define DI_OFF     134479872
#define C_OFF      134742016
#define NFILL4     16777216   // float4 count per A matrix (1024*256*64)
#define ND4        65536      // float4 count of one D matrix
#define GEMM_BLOCKS 192       // 16 batch-tiles x 12 col-tiles
#define FILL_BLOCKS 2048
#define FILL_THREADS (FILL_BLOCKS * 256)   // 524288 -> 32 iters over NFILL4

typedef __attribute__((ext_vector_type(8))) short bf16x8;
typedef __attribute__((ext_vector_type(4))) float f32x4;

// round-to-nearest-even fp32 -> bf16 bits
__device__ inline short bf16_rne(float f) {
    unsigned u = __float_as_uint(f);
    unsigned r = (u + 0x7FFFu + ((u >> 16) & 1u)) >> 16;
    return (short)r;
}

// split f into hi (bf16) + lo (bf16 of remainder)
__device__ inline void split8(const float* f, bf16x8& hi, bf16x8& lo) {
    #pragma unroll
    for (int j = 0; j < 8; ++j) {
        short h = bf16_rne(f[j]);
        hi[j] = h;
        float hf = __uint_as_float(((unsigned)(unsigned short)h) << 16);
        lo[j] = bf16_rne(f[j] - hf);
    }
}

// Fused: blocks [0,192) = GEMM (theta->sincos full diag-chunk float4 writes,
// raw Dr/Di + norm atomics). Blocks [192, 192+2048) = grid-stride A-fill
// (skipping diagonal chunks, which GEMM owns) + C copy.
__global__ __launch_bounds__(256) void fused_kernel(
    const float* __restrict__ x,
    const float* __restrict__ Wt, const float* __restrict__ bt,
    const float* __restrict__ Wr, const float* __restrict__ br,
    const float* __restrict__ Wi, const float* __restrict__ bi,
    const float* __restrict__ Cin,
    float* __restrict__ out, float* __restrict__ wsn)
{
    const int bid = blockIdx.x;

    if (bid >= GEMM_BLOCKS) {
        // ---------------- fill path (grid-stride) ----------------
        int gtid = (bid - GEMM_BLOCKS) * 256 + threadIdx.x;   // [0, 524288)
        if (gtid < 1024)      // C = 1024 float4
            *(float4*)(out + C_OFF + 4 * gtid) = *(const float4*)(Cin + 4 * gtid);

        const int c4 = gtid & 63;          // float4 col-chunk within row (const)
        const int m  = (gtid >> 6) & 255;  // row within matrix (const: stride%16384==0)
        if (c4 == (m >> 2)) return;        // diagonal chunk: GEMM writes it

        const float4 z = make_float4(0.f, 0.f, 0.f, 0.f);
        float* pr = out + 4 * (size_t)gtid;
        float* pi = pr + A_IMAG_OFF;
        #pragma unroll 8
        for (int it = 0; it < 32; ++it) {
            *(float4*)pr = z;
            *(float4*)pi = z;
            pr += 4 * FILL_THREADS;
            pi += 4 * FILL_THREADS;
        }
        return;
    }

    // ---------------- GEMM path ----------------
    const int b0  = (bid & 15) * 64;       // batch tile
    const int n0g = (bid >> 4) * 64;       // output-col tile over 768
    const int mat = n0g >> 8;              // 0=theta 1=Dr 2=Di
    const int n0  = n0g & 255;
    const float* __restrict__ W    = (mat == 0) ? Wt : (mat == 1) ? Wr : Wi;
    const float* __restrict__ bias = (mat == 0) ? bt : (mat == 1) ? br : bi;

    const int t  = threadIdx.x;
    const int l  = t & 63;
    const int w  = t >> 6;                 // wave id 0..3
    const int wr = w >> 1, wc = w & 1;     // 2x2 wave grid (32x32 each)
    const int lr = l & 15;
    const int kg = l >> 4;                 // k-group (8 consecutive k)

    const int arow0 = b0 + wr * 32 + lr;
    const int bcol0 = n0 + wc * 32 + lr;

    f32x4 acc[2][2] = {};

    for (int f0 = 0; f0 < FEAT; f0 += 32) {
        const int ks = f0 + kg * 8;
        bf16x8 ah[2], al[2], bh[2], bl[2];
        #pragma unroll
        for (int mi = 0; mi < 2; ++mi) {
            const float* p = x + (size_t)(arow0 + mi * 16) * FEAT + ks;
            float4 v0 = *(const float4*)p, v1 = *(const float4*)(p + 4);
            float f[8] = {v0.x, v0.y, v0.z, v0.w, v1.x, v1.y, v1.z, v1.w};
            split8(f, ah[mi], al[mi]);
        }
        #pragma unroll
        for (int ni = 0; ni < 2; ++ni) {
            const float* p = W + (size_t)(bcol0 + ni * 16) * FEAT + ks;
            float4 v0 = *(const float4*)p, v1 = *(const float4*)(p + 4);
            float f[8] = {v0.x, v0.y, v0.z, v0.w, v1.x, v1.y, v1.z, v1.w};
            split8(f, bh[ni], bl[ni]);
        }
        #pragma unroll
        for (int mi = 0; mi < 2; ++mi)
            #pragma unroll
            for (int ni = 0; ni < 2; ++ni) {
                acc[mi][ni] = __builtin_amdgcn_mfma_f32_16x16x32_bf16(ah[mi], bh[ni], acc[mi][ni], 0, 0, 0);
                acc[mi][ni] = __builtin_amdgcn_mfma_f32_16x16x32_bf16(ah[mi], bl[ni], acc[mi][ni], 0, 0, 0);
                acc[mi][ni] = __builtin_amdgcn_mfma_f32_16x16x32_bf16(al[mi], bh[ni], acc[mi][ni], 0, 0, 0);
            }
    }

    float y[2][2][4];
    #pragma unroll
    for (int mi = 0; mi < 2; ++mi)
        #pragma unroll
        for (int ni = 0; ni < 2; ++ni) {
            float bv = bias[bcol0 + ni * 16];
            #pragma unroll
            for (int r = 0; r < 4; ++r)
                y[mi][ni][r] = acc[mi][ni][r] + bv;
        }

    if (mat == 0) {
        #pragma unroll
        for (int mi = 0; mi < 2; ++mi)
            #pragma unroll
            for (int ni = 0; ni < 2; ++ni)
                #pragma unroll
                for (int r = 0; r < 4; ++r) {
                    int b = b0 + wr * 32 + mi * 16 + kg * 4 + r;
                    int m = bcol0 + ni * 16;
                    float s, c;
                    sincosf(y[mi][ni][r], &s, &c);
                    // write the full 16B diagonal chunk (zeros + diag value)
                    float4 vr = make_float4(0.f, 0.f, 0.f, 0.f);
                    float4 vi = vr;
                    ((float*)&vr)[m & 3] = c;
                    ((float*)&vi)[m & 3] = s;
                    size_t off = (size_t)b * 65536 + m * 256 + (m >> 2) * 4;
                    *(float4*)(out + off) = vr;
                    *(float4*)(out + A_IMAG_OFF + off) = vi;
                }
    } else {
        const size_t base = (mat == 1) ? DR_OFF : DI_OFF;
        #pragma unroll
        for (int mi = 0; mi < 2; ++mi)
            #pragma unroll
            for (int ni = 0; ni < 2; ++ni)
                #pragma unroll
                for (int r = 0; r < 4; ++r) {
                    int b = b0 + wr * 32 + mi * 16 + kg * 4 + r;
                    out[base + (size_t)b * 256 + bcol0 + ni * 16] = y[mi][ni][r];
                }
        #pragma unroll
        for (int mi = 0; mi < 2; ++mi)
            #pragma unroll
            for (int r = 0; r < 4; ++r) {
                float v = y[mi][0][r] * y[mi][0][r] + y[mi][1][r] * y[mi][1][r];
                v += __shfl_xor(v, 1);
                v += __shfl_xor(v, 2);
                v += __shfl_xor(v, 4);
                v += __shfl_xor(v, 8);
                if (lr == 0)
                    atomicAdd(&wsn[b0 + wr * 32 + mi * 16 + kg * 4 + r], v);
            }
    }
}

// Scale Dr/Di in place by sqrt(10)/(4*sqrt(wsn[b])).
__global__ __launch_bounds__(256) void scale_kernel(
    float* __restrict__ out, const float* __restrict__ wsn)
{
    int q  = blockIdx.x * 256 + threadIdx.x;     // [0, 2*ND4)
    int qq = q & (ND4 - 1);
    int b  = qq >> 6;                            // 64 float4 per batch
    float scale = 0.7905694150420949f * rsqrtf(wsn[b]);  // sqrt(10)/4/sqrt(sum)
    float* p = out + ((q < ND4) ? DR_OFF : DI_OFF) + 4 * (size_t)qq;
    float4 v = *(float4*)p;
    v.x *= scale; v.y *= scale; v.z *= scale; v.w *= scale;
    *(float4*)p = v;
}

extern "C" void kernel_launch(void* const* d_in, const int* in_sizes, int n_in,
                              void* d_out, int out_size, void* d_ws, size_t ws_size,
                              hipStream_t stream)
{
    const float* x  = (const float*)d_in[0];
    const float* Wt = (const float*)d_in[1];
    const float* bt = (const float*)d_in[2];
    const float* Wr = (const float*)d_in[3];
    const float* br = (const float*)d_in[4];
    const float* Wi = (const float*)d_in[5];
    const float* bi = (const float*)d_in[6];
    const float* C  = (const float*)d_in[7];
    float* out = (float*)d_out;
    float* wsn = (float*)d_ws;   // 1024 floats: per-batch sum(Dr^2+Di^2)

    hipMemsetAsync(wsn, 0, 1024 * sizeof(float), stream);

    fused_kernel<<<GEMM_BLOCKS + FILL_BLOCKS, 256, 0, stream>>>(
        x, Wt, bt, Wr, br, Wi, bi, C, out, wsn);

    scale_kernel<<<2 * ND4 / 256, 256, 0, stream>>>(out, wsn);
}